// Round 2
// baseline (347.649 us; speedup 1.0000x reference)
//
#include <hip/hip_runtime.h>
#include <cstdint>

#define OWD 126
#define MTOT 15876   // 126*126

typedef short bf16x8 __attribute__((ext_vector_type(8)));
typedef float f32x4  __attribute__((ext_vector_type(4)));

#define BT_ELEMS  (16u * 128u * 1152u)                 // 2,359,296 bf16
#define XBF_ELEMS (16u * 128u * 128u * 128u)           // 33,554,432 bf16
#define WS_NEEDED ((size_t)(BT_ELEMS + XBF_ELEMS) * 2) // ~71.8 MB

__device__ __forceinline__ uint16_t f2bf(float f) {
    union { float f; uint32_t u; } v;
    v.f = f;
    uint32_t u = v.u;
    return (uint16_t)((u + 0x7FFFu + ((u >> 16) & 1u)) >> 16);
}

__device__ __forceinline__ uint32_t pk2(float a, float b) {
    return (uint32_t)f2bf(a) | ((uint32_t)f2bf(b) << 16);
}

__device__ __forceinline__ void gl_lds16(const uint16_t* g, uint16_t* l) {
    __builtin_amdgcn_global_load_lds(
        (const __attribute__((address_space(1))) uint32_t*)g,
        (__attribute__((address_space(3))) uint32_t*)l, 16, 0, 0);
}

// ---------------------------------------------------------------------------
// Prep 1: kernel [16][9][128 c][128 n] fp32 -> Bt [16][128 n][1152 k] bf16
// ---------------------------------------------------------------------------
__global__ __launch_bounds__(256) void kprep(const float* __restrict__ Kin,
                                             uint16_t* __restrict__ Bt) {
    const int rs = blockIdx.x;   // 0..8
    const int b  = blockIdx.y;   // 0..15
    const int t  = threadIdx.x;
    const int n  = t & 127;
    const int og = t >> 7;

    const float* src = Kin + (((size_t)b * 9 + rs) << 14);
    uint16_t*    dst = Bt + ((size_t)b * 128 + n) * 1152 + rs * 128;

#pragma unroll
    for (int o = 0; o < 8; ++o) {
        const int oct = og * 8 + o;
        const float* s0 = src + (oct * 8) * 128 + n;
        uint4 p;
        p.x = pk2(s0[0 * 128], s0[1 * 128]);
        p.y = pk2(s0[2 * 128], s0[3 * 128]);
        p.z = pk2(s0[4 * 128], s0[5 * 128]);
        p.w = pk2(s0[6 * 128], s0[7 * 128]);
        *(uint4*)(dst + oct * 8) = p;
    }
}

// ---------------------------------------------------------------------------
// Prep 2: X fp32 NHWC -> bf16 NHWC (same layout), 8 elems/thread
// ---------------------------------------------------------------------------
__global__ __launch_bounds__(256) void xprep(const float* __restrict__ X,
                                             uint16_t* __restrict__ Xbf) {
    const size_t i = ((size_t)blockIdx.x * 256 + threadIdx.x) * 8;
    const float4 a = *(const float4*)(X + i);
    const float4 b = *(const float4*)(X + i + 4);
    uint4 p;
    p.x = pk2(a.x, a.y);
    p.y = pk2(a.z, a.w);
    p.z = pk2(b.x, b.y);
    p.w = pk2(b.z, b.w);
    *(uint4*)(Xbf + i) = p;
}

// ---------------------------------------------------------------------------
// Main (round 2): 256x128 block tile, 4 waves, per-wave 128x64 register tile
// (acc 8x4 f32x4 = 128 VGPR). Rationale: LDS bandwidth was the leading floor
// (~19k cyc/block vs 11k MFMA); per-wave tile growth cuts LDS-read/FLOP 1.33x
// and B now bypasses LDS entirely: Bt panel (288 KB/batch) is L2-resident, so
// B fragments are loaded straight global->VGPR (no swizzle needed), double-
// buffered one chunk ahead; they drain for free under the pre-barrier
// vmcnt(0). LDS holds only A: [2 buf][256 rows][64 k] bf16 = 64 KB, XOR
// swizzle slot = kc^(row&7) as before (verified conflict-free).
// ---------------------------------------------------------------------------
__global__ __launch_bounds__(256, 2) void conv_mfma_b(const uint16_t* __restrict__ Xbf,
                                                      const uint16_t* __restrict__ Bt,
                                                      float* __restrict__ Out) {
    __shared__ __align__(16) uint16_t lA[2][256 * 64];

    const int mtile = blockIdx.x;  // 0..62
    const int b     = blockIdx.y;  // 0..15
    const int tid   = threadIdx.x;
    const int lane  = tid & 63;
    const int wave  = tid >> 6;
    const int wm    = (wave & 1) << 7;   // 0 / 128
    const int wn    = (wave >> 1) << 6;  // 0 / 64
    const int l15   = lane & 15;
    const int quad  = lane >> 4;

    // A staging: lane l, iter i covers LDS slot s = wave*512 + i*64 + lane
    //   row = s>>3 = wave*64 + i*8 + (lane>>3), pslot = lane&7
    //   logical chunk kc = pslot ^ (row&7) = (lane&7) ^ (lane>>3)
    const int kc = (lane & 7) ^ (lane >> 3);
    const uint16_t* Asrc[8];
#pragma unroll
    for (int i = 0; i < 8; ++i) {
        const int row = wave * 64 + i * 8 + (lane >> 3);
        int m = mtile * 256 + row;
        if (m >= MTOT) m = MTOT - 1;
        const int oh = m / OWD, ow = m - oh * OWD;
        Asrc[i] = Xbf + (((size_t)b * 128 + oh) * 128 + ow) * 128 + kc * 8;
    }
    uint16_t* Ad0 = &lA[0][(wave * 512 + lane) * 8];
    uint16_t* Ad1 = &lA[1][(wave * 512 + lane) * 8];

    // B fragment bases: row = wn + j*16 + l15, k-offset quad*8 (+ksub*32)
    const uint16_t* Bp[4];
#pragma unroll
    for (int j = 0; j < 4; ++j)
        Bp[j] = Bt + ((size_t)b * 128 + wn + j * 16 + l15) * 1152 + quad * 8;

    f32x4 acc[8][4];
#pragma unroll
    for (int i = 0; i < 8; ++i)
#pragma unroll
        for (int j = 0; j < 4; ++j)
            acc[i][j] = (f32x4){0.f, 0.f, 0.f, 0.f};

    bf16x8 bA[8], bB[8];   // [j*2 + ksub], double-buffered B fragments

    // chunk t (0..17): rs = t>>1, k-half c0 = (t&1)*64
#define STAGE(t_, Ad_)                                                      \
    {                                                                       \
        const int rs_ = (t_) >> 1;                                         \
        const int c0_ = ((t_) & 1) << 6;                                   \
        const int r_  = (rs_ * 11) >> 5; /* rs/3 for rs<9 */               \
        const int s_  = rs_ - r_ * 3;                                      \
        const int ao_ = (r_ * 128 + s_) * 128 + c0_;                       \
        _Pragma("unroll")                                                  \
        for (int i_ = 0; i_ < 8; ++i_)                                     \
            gl_lds16(Asrc[i_] + ao_, Ad_ + i_ * 512);                      \
    }

#define LOADB(t_, br_)                                                      \
    {                                                                       \
        const int off_ = ((t_) >> 1) * 128 + (((t_) & 1) << 6);            \
        _Pragma("unroll")                                                  \
        for (int j_ = 0; j_ < 4; ++j_) {                                   \
            br_[j_ * 2 + 0] = *(const bf16x8*)(Bp[j_] + off_);             \
            br_[j_ * 2 + 1] = *(const bf16x8*)(Bp[j_] + off_ + 32);        \
        }                                                                  \
    }

#define COMPUTE(bu_, br_)                                                   \
    {                                                                       \
        _Pragma("unroll")                                                  \
        for (int ksub_ = 0; ksub_ < 2; ++ksub_) {                          \
            _Pragma("unroll")                                              \
            for (int ih_ = 0; ih_ < 2; ++ih_) {                            \
                bf16x8 af[4];                                              \
                _Pragma("unroll")                                          \
                for (int i_ = 0; i_ < 4; ++i_) {                           \
                    const int row_ = wm + (ih_ * 4 + i_) * 16 + l15;       \
                    const int pc_  = (ksub_ * 4 + quad) ^ (row_ & 7);      \
                    af[i_] = *(const bf16x8*)&lA[bu_][row_ * 64 + pc_ * 8];\
                }                                                          \
                _Pragma("unroll")                                          \
                for (int i_ = 0; i_ < 4; ++i_)                             \
                    _Pragma("unroll")                                      \
                    for (int j_ = 0; j_ < 4; ++j_)                         \
                        acc[ih_ * 4 + i_][j_] =                            \
                            __builtin_amdgcn_mfma_f32_16x16x32_bf16(       \
                                af[i_], br_[j_ * 2 + ksub_],               \
                                acc[ih_ * 4 + i_][j_], 0, 0, 0);           \
            }                                                              \
        }                                                                  \
    }

    // prologue: chunk 0 (A -> buf0, B -> bA); barrier drains the gl_lds.
    LOADB(0, bA);
    STAGE(0, Ad0);
    __syncthreads();

    // steady state, unroll x2. B(t+1)/A(t+1) issued before COMPUTE(t); the
    // end-of-iter barrier's implicit vmcnt(0) drains both (LOADB precedes
    // STAGE, and vmcnt is in-order).
#pragma unroll 1
    for (int t = 0; t < 16; t += 2) {
        LOADB(t + 1, bB);
        STAGE(t + 1, Ad1);
        COMPUTE(0, bA);
        __syncthreads();
        LOADB(t + 2, bA);
        STAGE(t + 2, Ad0);
        COMPUTE(1, bB);
        __syncthreads();
    }
    // computed 0..15, staged 0..16, B loaded 0..16. Tail: 16 (buf0,bA), 17.
    LOADB(17, bB);
    STAGE(17, Ad1);
    COMPUTE(0, bA);
    __syncthreads();
    COMPUTE(1, bB);

#undef STAGE
#undef LOADB
#undef COMPUTE

    // epilogue: D row = quad*4+reg, col = lane&15 (verified)
#pragma unroll
    for (int i = 0; i < 8; ++i) {
#pragma unroll
        for (int rr = 0; rr < 4; ++rr) {
            const int mrow = mtile * 256 + wm + i * 16 + quad * 4 + rr;
            if (mrow < MTOT) {
                const int oh2 = mrow / OWD;
                const int ow2 = mrow - oh2 * OWD;
                float* op = Out + (((size_t)b * OWD + oh2) * OWD + ow2) * 128 + wn + l15;
#pragma unroll
                for (int j = 0; j < 4; ++j)
                    op[j * 16] = acc[i][j][rr];
            }
        }
    }
}

// ---------------------------------------------------------------------------
// Fallback (ws too small): fp32 X with in-kernel cvt (unchanged, verified).
// ---------------------------------------------------------------------------
__global__ __launch_bounds__(256) void conv_mfma(const float* __restrict__ X,
                                                 const uint16_t* __restrict__ Bt,
                                                 float* __restrict__ Out) {
    __shared__ __align__(16) uint16_t lA[128 * 64];
    __shared__ __align__(16) uint16_t lB[128 * 64];

    const int mtile = blockIdx.x;
    const int b     = blockIdx.y;
    const int tid   = threadIdx.x;
    const int lane  = tid & 63;
    const int wave  = tid >> 6;
    const int wm    = (wave & 1) << 6;
    const int wn    = (wave >> 1) << 6;
    const int l15   = lane & 15;
    const int quad  = lane >> 4;

    const int srow  = tid >> 1;
    const int shalf = tid & 1;

    int m = mtile * 128 + srow;
    if (m >= MTOT) m = MTOT - 1;
    const int oh = m / OWD;
    const int ow = m - oh * OWD;
    const float*    Xb = X + (((size_t)b * 128 + oh) * 128 + ow) * 128;
    const uint16_t* Bb = Bt + ((size_t)b * 128 + srow) * 1152 + shalf * 32;

    f32x4 acc[4][4];
#pragma unroll
    for (int i = 0; i < 4; ++i)
#pragma unroll
        for (int j = 0; j < 4; ++j)
            acc[i][j] = (f32x4){0.f, 0.f, 0.f, 0.f};

    for (int chunk = 0; chunk < 18; ++chunk) {
        const int rs = chunk >> 1;
        const int c0 = (chunk & 1) << 6;
        const int r  = rs / 3;
        const int s  = rs - r * 3;

        __syncthreads();
        {
            const float4* src = (const float4*)(Xb + (r * 128 + s) * 128 + c0 + shalf * 32);
            float4 v[8];
#pragma unroll
            for (int i = 0; i < 8; ++i) v[i] = src[i];
#pragma unroll
            for (int i = 0; i < 4; ++i) {
                uint4 p;
                p.x = pk2(v[2 * i].x, v[2 * i].y);
                p.y = pk2(v[2 * i].z, v[2 * i].w);
                p.z = pk2(v[2 * i + 1].x, v[2 * i + 1].y);
                p.w = pk2(v[2 * i + 1].z, v[2 * i + 1].w);
                const int ci = (shalf * 4 + i) ^ (srow & 7);
                *(uint4*)&lA[srow * 64 + ci * 8] = p;
            }
        }
        {
            const uint4* bsrc = (const uint4*)(Bb + rs * 128 + c0);
#pragma unroll
            for (int i = 0; i < 4; ++i) {
                const uint4 p = bsrc[i];
                const int ci = (shalf * 4 + i) ^ (srow & 7);
                *(uint4*)&lB[srow * 64 + ci * 8] = p;
            }
        }
        __syncthreads();

#pragma unroll
        for (int ksub = 0; ksub < 2; ++ksub) {
            bf16x8 af[4], bfr[4];
#pragma unroll
            for (int i = 0; i < 4; ++i) {
                const int row = wm + i * 16 + l15;
                const int ci  = (ksub * 4 + quad) ^ (row & 7);
                af[i] = *(const bf16x8*)&lA[row * 64 + ci * 8];
            }
#pragma unroll
            for (int j = 0; j < 4; ++j) {
                const int row = wn + j * 16 + l15;
                const int ci  = (ksub * 4 + quad) ^ (row & 7);
                bfr[j] = *(const bf16x8*)&lB[row * 64 + ci * 8];
            }
#pragma unroll
            for (int i = 0; i < 4; ++i)
#pragma unroll
                for (int j = 0; j < 4; ++j)
                    acc[i][j] = __builtin_amdgcn_mfma_f32_16x16x32_bf16(
                        af[i], bfr[j], acc[i][j], 0, 0, 0);
        }
    }

#pragma unroll
    for (int i = 0; i < 4; ++i) {
#pragma unroll
        for (int rr = 0; rr < 4; ++rr) {
            const int mrow = mtile * 128 + wm + i * 16 + quad * 4 + rr;
            if (mrow < MTOT) {
                const int oh2 = mrow / OWD;
                const int ow2 = mrow - oh2 * OWD;
                float* op = Out + (((size_t)b * OWD + oh2) * OWD + ow2) * 128 + wn + l15;
#pragma unroll
                for (int j = 0; j < 4; ++j)
                    op[j * 16] = acc[i][j][rr];
            }
        }
    }
}

extern "C" void kernel_launch(void* const* d_in, const int* in_sizes, int n_in,
                              void* d_out, int out_size, void* d_ws, size_t ws_size,
                              hipStream_t stream) {
    const float* X   = (const float*)d_in[0];   // [16,128,128,128]
    const float* Kin = (const float*)d_in[1];   // [16,3,3,128,128]
    float*       Out = (float*)d_out;           // [16,126,126,128]
    uint16_t*    Bt  = (uint16_t*)d_ws;         // bf16 [16][128][1152]
    uint16_t*    Xbf = Bt + BT_ELEMS;           // bf16 [16][128][128][128]

    kprep<<<dim3(9, 16), 256, 0, stream>>>(Kin, Bt);
    if (ws_size >= WS_NEEDED) {
        xprep<<<XBF_ELEMS / (256 * 8), 256, 0, stream>>>(X, Xbf);
        conv_mfma_b<<<dim3(63, 16), 256, 0, stream>>>(Xbf, Bt, Out);
    } else {
        conv_mfma<<<dim3(125, 16), 256, 0, stream>>>(X, Bt, Out);
    }
}

// Round 3
// 325.756 us; speedup vs baseline: 1.0672x; 1.0672x over previous
//
#include <hip/hip_runtime.h>
#include <cstdint>

#define OWD 126
#define MTOT 15876   // 126*126

typedef short bf16x8 __attribute__((ext_vector_type(8)));
typedef float f32x4  __attribute__((ext_vector_type(4)));

#define BT_ELEMS  (16u * 128u * 1152u)                 // 2,359,296 bf16
#define XBF_ELEMS (16u * 128u * 128u * 128u)           // 33,554,432 bf16
#define WS_NEEDED ((size_t)(BT_ELEMS + XBF_ELEMS) * 2) // ~71.8 MB

__device__ __forceinline__ uint16_t f2bf(float f) {
    union { float f; uint32_t u; } v;
    v.f = f;
    uint32_t u = v.u;
    return (uint16_t)((u + 0x7FFFu + ((u >> 16) & 1u)) >> 16);
}

__device__ __forceinline__ uint32_t pk2(float a, float b) {
    return (uint32_t)f2bf(a) | ((uint32_t)f2bf(b) << 16);
}

__device__ __forceinline__ void gl_lds16(const uint16_t* g, uint16_t* l) {
    __builtin_amdgcn_global_load_lds(
        (const __attribute__((address_space(1))) uint32_t*)g,
        (__attribute__((address_space(3))) uint32_t*)l, 16, 0, 0);
}

// ---------------------------------------------------------------------------
// Prep 1: kernel [16][9][128 c][128 n] fp32 -> Bt [16][128 n][1152 k] bf16
// ---------------------------------------------------------------------------
__global__ __launch_bounds__(256) void kprep(const float* __restrict__ Kin,
                                             uint16_t* __restrict__ Bt) {
    const int rs = blockIdx.x;   // 0..8
    const int b  = blockIdx.y;   // 0..15
    const int t  = threadIdx.x;
    const int n  = t & 127;
    const int og = t >> 7;

    const float* src = Kin + (((size_t)b * 9 + rs) << 14);
    uint16_t*    dst = Bt + ((size_t)b * 128 + n) * 1152 + rs * 128;

#pragma unroll
    for (int o = 0; o < 8; ++o) {
        const int oct = og * 8 + o;
        const float* s0 = src + (oct * 8) * 128 + n;
        uint4 p;
        p.x = pk2(s0[0 * 128], s0[1 * 128]);
        p.y = pk2(s0[2 * 128], s0[3 * 128]);
        p.z = pk2(s0[4 * 128], s0[5 * 128]);
        p.w = pk2(s0[6 * 128], s0[7 * 128]);
        *(uint4*)(dst + oct * 8) = p;
    }
}

// ---------------------------------------------------------------------------
// Prep 2: X fp32 NHWC -> bf16 NHWC (same layout), 8 elems/thread
// ---------------------------------------------------------------------------
__global__ __launch_bounds__(256) void xprep(const float* __restrict__ X,
                                             uint16_t* __restrict__ Xbf) {
    const size_t i = ((size_t)blockIdx.x * 256 + threadIdx.x) * 8;
    const float4 a = *(const float4*)(X + i);
    const float4 b = *(const float4*)(X + i + 4);
    uint4 p;
    p.x = pk2(a.x, a.y);
    p.y = pk2(a.z, a.w);
    p.z = pk2(b.x, b.y);
    p.w = pk2(b.z, b.w);
    *(uint4*)(Xbf + i) = p;
}

// ---------------------------------------------------------------------------
// Main (round 3): 128x128 block tile (round-1 geometry, reverted from the
// round-2 regression), 4 waves, wave tile 64x64. Structural change = T3+T4:
//   BK=32, 36 K-chunks, THREE 16 KB LDS buffers (48 KB -> 3 blocks/CU),
//   depth-2 prefetch, per chunk: { s_waitcnt vmcnt(4); s_barrier;
//   STAGE(t+2); COMPUTE(t); } -- counted vmcnt keeps chunks t+1/t+2 in
//   flight ACROSS the barrier (never drains to 0 in the loop).
// Hazards: wait-before-barrier => all waves drained their own chunk-t loads
// before anyone reads buf(t%3); STAGE(t+2) overwrites buf((t-1)%3) whose
// readers (COMPUTE(t-1)) finished before this iteration's barrier.
// LDS layout: [3 bufs][256 rows][32 ch] bf16 (A rows 0..127, B rows
// 128..255), 64B rows of four 16B slots; logical slot q of row r lives at
// q^(r&3). Staging lane l fetches kc=(l&3)^((l>>2)&3) so its linear gl_lds
// dst holds the right data; reads are <=2-way bank aliased (free, m136).
// T1 XCD swizzle: 2000 blocks % 8 == 0 -> consecutive m-tiles (sharing 2 of
// 3 input rows) land on the same XCD L2.
// ---------------------------------------------------------------------------
__global__ __launch_bounds__(256) void conv_mfma_c(const uint16_t* __restrict__ Xbf,
                                                   const uint16_t* __restrict__ Bt,
                                                   float* __restrict__ Out) {
    __shared__ __align__(16) uint16_t lds[3][256 * 32];  // 3 x 16 KB

    // XCD-aware bijective swizzle (nwg = 125*16 = 2000, 2000 % 8 == 0)
    const int id    = blockIdx.x + 125 * blockIdx.y;
    const int nid   = (id & 7) * 250 + (id >> 3);
    const int mtile = nid % 125;
    const int b     = nid / 125;

    const int tid  = threadIdx.x;
    const int lane = tid & 63;
    const int wave = tid >> 6;
    const int wm   = (wave & 1) << 6;
    const int wn   = (wave >> 1) << 6;
    const int l15  = lane & 15;
    const int quad = lane >> 4;

    // staging: wave w stages A rows w*32..w*32+31 and B rows w*32..w*32+31.
    // load i (0,1): 1 KB = rows w*32+i*16+(lane>>2), phys slot lane&3,
    // logical chunk kc = (lane&3) ^ ((lane>>2)&3)   (row&3 == (lane>>2)&3)
    const int l2 = lane >> 2;
    const int kc = (lane & 3) ^ (l2 & 3);
    const uint16_t* Asrc[2];
    const uint16_t* Bsrc[2];
#pragma unroll
    for (int i = 0; i < 2; ++i) {
        const int row = wave * 32 + i * 16 + l2;
        int m = mtile * 128 + row;
        if (m >= MTOT) m = MTOT - 1;
        const int oh = m / OWD, ow = m - oh * OWD;
        Asrc[i] = Xbf + (((size_t)b * 128 + oh) * 128 + ow) * 128 + kc * 8;
        Bsrc[i] = Bt + ((size_t)b * 128 + row) * 1152 + kc * 8;
    }
    const int dbase = wave * 1024 + lane * 8;  // elem offset in a buffer

    f32x4 acc[4][4];
#pragma unroll
    for (int i = 0; i < 4; ++i)
#pragma unroll
        for (int j = 0; j < 4; ++j)
            acc[i][j] = (f32x4){0.f, 0.f, 0.f, 0.f};

    // chunk t (0..35): rs = t>>2, ch base c0 = (t&3)*32
#define STAGE(t_, bu_)                                                      \
    {                                                                       \
        const int rs_ = (t_) >> 2;                                         \
        const int c0_ = ((t_) & 3) << 5;                                   \
        const int r_  = (rs_ * 11) >> 5; /* rs/3 for rs<9 */               \
        const int s_  = rs_ - r_ * 3;                                      \
        const int ao_ = (r_ * 128 + s_) * 128 + c0_;                       \
        const int bo_ = rs_ * 128 + c0_;                                   \
        uint16_t* Ad_ = &lds[bu_][dbase];                                  \
        uint16_t* Bd_ = &lds[bu_][4096 + dbase];                           \
        _Pragma("unroll")                                                  \
        for (int i_ = 0; i_ < 2; ++i_) {                                   \
            gl_lds16(Asrc[i_] + ao_, Ad_ + i_ * 512);                      \
            gl_lds16(Bsrc[i_] + bo_, Bd_ + i_ * 512);                      \
        }                                                                  \
    }

#define COMPUTE(bu_)                                                        \
    {                                                                       \
        bf16x8 af[4], bfr[4];                                              \
        _Pragma("unroll")                                                  \
        for (int i_ = 0; i_ < 4; ++i_) {                                   \
            const int row_ = wm + i_ * 16 + l15;                           \
            const int sl_  = quad ^ (row_ & 3);                            \
            af[i_] = *(const bf16x8*)&lds[bu_][row_ * 32 + sl_ * 8];       \
        }                                                                  \
        _Pragma("unroll")                                                  \
        for (int j_ = 0; j_ < 4; ++j_) {                                   \
            const int row_ = wn + j_ * 16 + l15;                           \
            const int sl_  = quad ^ (row_ & 3);                            \
            bfr[j_] = *(const bf16x8*)&lds[bu_][4096 + row_ * 32 + sl_ * 8];\
        }                                                                  \
        _Pragma("unroll")                                                  \
        for (int i_ = 0; i_ < 4; ++i_)                                     \
            _Pragma("unroll")                                              \
            for (int j_ = 0; j_ < 4; ++j_)                                 \
                acc[i_][j_] = __builtin_amdgcn_mfma_f32_16x16x32_bf16(     \
                    af[i_], bfr[j_], acc[i_][j_], 0, 0, 0);                \
    }

#define WAITBAR4                                                            \
    asm volatile("s_waitcnt vmcnt(4)" ::: "memory");                       \
    __builtin_amdgcn_s_barrier();                                          \
    __builtin_amdgcn_sched_barrier(0);

#define ITER(t_, bc_, bs_)                                                  \
    {                                                                       \
        WAITBAR4;                                                          \
        STAGE((t_) + 2, bs_);                                              \
        COMPUTE(bc_);                                                      \
    }

    // prologue: chunks 0,1 into bufs 0,1 (8 loads in flight)
    STAGE(0, 0);
    STAGE(1, 1);

    // steady state: compute t from buf t%3, stage t+2 into (t+2)%3.
    // At each wait: outstanding = chunk t (4) + chunk t+1 (4); vmcnt(4)
    // drains t's, leaves t+1's in flight across the barrier.
#pragma unroll 1
    for (int t = 0; t < 33; t += 3) {
        ITER(t, 0, 2);
        ITER(t + 1, 1, 0);
        ITER(t + 2, 2, 1);
    }
    ITER(33, 0, 2);  // stages chunk 35 into buf 2
    // t = 34: outstanding = 34's + 35's -> drain 34's
    WAITBAR4;
    COMPUTE(1);
    // t = 35: drain the last 4
    asm volatile("s_waitcnt vmcnt(0)" ::: "memory");
    __builtin_amdgcn_s_barrier();
    __builtin_amdgcn_sched_barrier(0);
    COMPUTE(2);

#undef STAGE
#undef COMPUTE
#undef WAITBAR4
#undef ITER

    // epilogue: D row = quad*4+reg, col = lane&15 (verified)
#pragma unroll
    for (int i = 0; i < 4; ++i) {
#pragma unroll
        for (int rr = 0; rr < 4; ++rr) {
            const int mrow = mtile * 128 + wm + i * 16 + quad * 4 + rr;
            if (mrow < MTOT) {
                const int oh2 = mrow / OWD;
                const int ow2 = mrow - oh2 * OWD;
                float* op = Out + (((size_t)b * OWD + oh2) * OWD + ow2) * 128 + wn + l15;
#pragma unroll
                for (int j = 0; j < 4; ++j)
                    op[j * 16] = acc[i][j][rr];
            }
        }
    }
}

// ---------------------------------------------------------------------------
// Fallback (ws too small): fp32 X with in-kernel cvt (unchanged, verified).
// ---------------------------------------------------------------------------
__global__ __launch_bounds__(256) void conv_mfma(const float* __restrict__ X,
                                                 const uint16_t* __restrict__ Bt,
                                                 float* __restrict__ Out) {
    __shared__ __align__(16) uint16_t lA[128 * 64];
    __shared__ __align__(16) uint16_t lB[128 * 64];

    const int mtile = blockIdx.x;
    const int b     = blockIdx.y;
    const int tid   = threadIdx.x;
    const int lane  = tid & 63;
    const int wave  = tid >> 6;
    const int wm    = (wave & 1) << 6;
    const int wn    = (wave >> 1) << 6;
    const int l15   = lane & 15;
    const int quad  = lane >> 4;

    const int srow  = tid >> 1;
    const int shalf = tid & 1;

    int m = mtile * 128 + srow;
    if (m >= MTOT) m = MTOT - 1;
    const int oh = m / OWD;
    const int ow = m - oh * OWD;
    const float*    Xb = X + (((size_t)b * 128 + oh) * 128 + ow) * 128;
    const uint16_t* Bb = Bt + ((size_t)b * 128 + srow) * 1152 + shalf * 32;

    f32x4 acc[4][4];
#pragma unroll
    for (int i = 0; i < 4; ++i)
#pragma unroll
        for (int j = 0; j < 4; ++j)
            acc[i][j] = (f32x4){0.f, 0.f, 0.f, 0.f};

    for (int chunk = 0; chunk < 18; ++chunk) {
        const int rs = chunk >> 1;
        const int c0 = (chunk & 1) << 6;
        const int r  = rs / 3;
        const int s  = rs - r * 3;

        __syncthreads();
        {
            const float4* src = (const float4*)(Xb + (r * 128 + s) * 128 + c0 + shalf * 32);
            float4 v[8];
#pragma unroll
            for (int i = 0; i < 8; ++i) v[i] = src[i];
#pragma unroll
            for (int i = 0; i < 4; ++i) {
                uint4 p;
                p.x = pk2(v[2 * i].x, v[2 * i].y);
                p.y = pk2(v[2 * i].z, v[2 * i].w);
                p.z = pk2(v[2 * i + 1].x, v[2 * i + 1].y);
                p.w = pk2(v[2 * i + 1].z, v[2 * i + 1].w);
                const int ci = (shalf * 4 + i) ^ (srow & 7);
                *(uint4*)&lA[srow * 64 + ci * 8] = p;
            }
        }
        {
            const uint4* bsrc = (const uint4*)(Bb + rs * 128 + c0);
#pragma unroll
            for (int i = 0; i < 4; ++i) {
                const uint4 p = bsrc[i];
                const int ci = (shalf * 4 + i) ^ (srow & 7);
                *(uint4*)&lB[srow * 64 + ci * 8] = p;
            }
        }
        __syncthreads();

#pragma unroll
        for (int ksub = 0; ksub < 2; ++ksub) {
            bf16x8 af[4], bfr[4];
#pragma unroll
            for (int i = 0; i < 4; ++i) {
                const int row = wm + i * 16 + l15;
                const int ci  = (ksub * 4 + quad) ^ (row & 7);
                af[i] = *(const bf16x8*)&lA[row * 64 + ci * 8];
            }
#pragma unroll
            for (int j = 0; j < 4; ++j) {
                const int row = wn + j * 16 + l15;
                const int ci  = (ksub * 4 + quad) ^ (row & 7);
                bfr[j] = *(const bf16x8*)&lB[row * 64 + ci * 8];
            }
#pragma unroll
            for (int i = 0; i < 4; ++i)
#pragma unroll
                for (int j = 0; j < 4; ++j)
                    acc[i][j] = __builtin_amdgcn_mfma_f32_16x16x32_bf16(
                        af[i], bfr[j], acc[i][j], 0, 0, 0);
        }
    }

#pragma unroll
    for (int i = 0; i < 4; ++i) {
#pragma unroll
        for (int rr = 0; rr < 4; ++rr) {
            const int mrow = mtile * 128 + wm + i * 16 + quad * 4 + rr;
            if (mrow < MTOT) {
                const int oh2 = mrow / OWD;
                const int ow2 = mrow - oh2 * OWD;
                float* op = Out + (((size_t)b * OWD + oh2) * OWD + ow2) * 128 + wn + l15;
#pragma unroll
                for (int j = 0; j < 4; ++j)
                    op[j * 16] = acc[i][j][rr];
            }
        }
    }
}

extern "C" void kernel_launch(void* const* d_in, const int* in_sizes, int n_in,
                              void* d_out, int out_size, void* d_ws, size_t ws_size,
                              hipStream_t stream) {
    const float* X   = (const float*)d_in[0];   // [16,128,128,128]
    const float* Kin = (const float*)d_in[1];   // [16,3,3,128,128]
    float*       Out = (float*)d_out;           // [16,126,126,128]
    uint16_t*    Bt  = (uint16_t*)d_ws;         // bf16 [16][128][1152]
    uint16_t*    Xbf = Bt + BT_ELEMS;           // bf16 [16][128][128][128]

    kprep<<<dim3(9, 16), 256, 0, stream>>>(Kin, Bt);
    if (ws_size >= WS_NEEDED) {
        xprep<<<XBF_ELEMS / (256 * 8), 256, 0, stream>>>(X, Xbf);
        conv_mfma_c<<<dim3(125, 16), 256, 0, stream>>>(Xbf, Bt, Out);
    } else {
        conv_mfma<<<dim3(125, 16), 256, 0, stream>>>(X, Bt, Out);
    }
}

// Round 4
// 322.685 us; speedup vs baseline: 1.0774x; 1.0095x over previous
//
#include <hip/hip_runtime.h>
#include <cstdint>

#define OWD 126
#define MTOT 15876   // 126*126

typedef short bf16x8 __attribute__((ext_vector_type(8)));
typedef float f32x4  __attribute__((ext_vector_type(4)));

#define BT_ELEMS  (16u * 128u * 1152u)                 // 2,359,296 bf16
#define XBF_ELEMS (16u * 128u * 128u * 128u)           // 33,554,432 bf16
#define WS_NEEDED ((size_t)(BT_ELEMS + XBF_ELEMS) * 2) // ~71.8 MB

__device__ __forceinline__ uint16_t f2bf(float f) {
    union { float f; uint32_t u; } v;
    v.f = f;
    uint32_t u = v.u;
    return (uint16_t)((u + 0x7FFFu + ((u >> 16) & 1u)) >> 16);
}

__device__ __forceinline__ uint32_t pk2(float a, float b) {
    return (uint32_t)f2bf(a) | ((uint32_t)f2bf(b) << 16);
}

__device__ __forceinline__ void gl_lds16(const uint16_t* g, uint16_t* l) {
    __builtin_amdgcn_global_load_lds(
        (const __attribute__((address_space(1))) uint32_t*)g,
        (__attribute__((address_space(3))) uint32_t*)l, 16, 0, 0);
}

// ---------------------------------------------------------------------------
// Prep 1: kernel [16][9][128 c][128 n] fp32 -> Bt [16][128 n][1152 k] bf16
// ---------------------------------------------------------------------------
__global__ __launch_bounds__(256) void kprep(const float* __restrict__ Kin,
                                             uint16_t* __restrict__ Bt) {
    const int rs = blockIdx.x;   // 0..8
    const int b  = blockIdx.y;   // 0..15
    const int t  = threadIdx.x;
    const int n  = t & 127;
    const int og = t >> 7;

    const float* src = Kin + (((size_t)b * 9 + rs) << 14);
    uint16_t*    dst = Bt + ((size_t)b * 128 + n) * 1152 + rs * 128;

#pragma unroll
    for (int o = 0; o < 8; ++o) {
        const int oct = og * 8 + o;
        const float* s0 = src + (oct * 8) * 128 + n;
        uint4 p;
        p.x = pk2(s0[0 * 128], s0[1 * 128]);
        p.y = pk2(s0[2 * 128], s0[3 * 128]);
        p.z = pk2(s0[4 * 128], s0[5 * 128]);
        p.w = pk2(s0[6 * 128], s0[7 * 128]);
        *(uint4*)(dst + oct * 8) = p;
    }
}

// ---------------------------------------------------------------------------
// Prep 2: X fp32 NHWC -> bf16 NHWC (same layout), 8 elems/thread
// ---------------------------------------------------------------------------
__global__ __launch_bounds__(256) void xprep(const float* __restrict__ X,
                                             uint16_t* __restrict__ Xbf) {
    const size_t i = ((size_t)blockIdx.x * 256 + threadIdx.x) * 8;
    const float4 a = *(const float4*)(X + i);
    const float4 b = *(const float4*)(X + i + 4);
    uint4 p;
    p.x = pk2(a.x, a.y);
    p.y = pk2(a.z, a.w);
    p.z = pk2(b.x, b.y);
    p.w = pk2(b.z, b.w);
    *(uint4*)(Xbf + i) = p;
}

// ---------------------------------------------------------------------------
// Main (round 4): identical to round 3 (BK=32, 36 chunks, 3x16KB LDS bufs,
// depth-2 prefetch, counted vmcnt(4) + s_barrier per chunk, XCD swizzle)
// EXCEPT the LDS XOR swizzle bit. Round 3 used slot = q ^ (row&3): row&1
// (bank-half) and row&3 (slot) are correlated, so a quarter-wave's 16 rows
// hit only 4 of 8 bank-quads -> 4-way conflict, 9.2M cycles/dispatch (~15us,
// cancelled the pipeline win). Fix: slot = q ^ ((row>>1)&3). Over 16
// consecutive rows, (row&1, (row>>1)&3) enumerates all 8 (parity,slot)
// combos exactly twice -> all 32 banks 2-way = free (m136).
// Both sides change together (rule #21): staging lane l covers LDS row
// ...+(l>>2), pslot l&3, so logical chunk kc = (l&3) ^ ((l>>3)&3); reads use
// slot = quad ^ ((row>>1)&3). Same involution on write and read.
// ---------------------------------------------------------------------------
__global__ __launch_bounds__(256) void conv_mfma_c(const uint16_t* __restrict__ Xbf,
                                                   const uint16_t* __restrict__ Bt,
                                                   float* __restrict__ Out) {
    __shared__ __align__(16) uint16_t lds[3][256 * 32];  // 3 x 16 KB

    // XCD-aware bijective swizzle (nwg = 125*16 = 2000, 2000 % 8 == 0)
    const int id    = blockIdx.x + 125 * blockIdx.y;
    const int nid   = (id & 7) * 250 + (id >> 3);
    const int mtile = nid % 125;
    const int b     = nid / 125;

    const int tid  = threadIdx.x;
    const int lane = tid & 63;
    const int wave = tid >> 6;
    const int wm   = (wave & 1) << 6;
    const int wn   = (wave >> 1) << 6;
    const int l15  = lane & 15;
    const int quad = lane >> 4;

    // staging: wave w stages A rows w*32..w*32+31 and B rows w*32..w*32+31.
    // load i (0,1): rows w*32+i*16+(lane>>2), phys slot lane&3,
    // logical chunk kc = (lane&3) ^ ((row>>1)&3) = (lane&3) ^ ((lane>>3)&3)
    const int l2 = lane >> 2;
    const int kc = (lane & 3) ^ ((lane >> 3) & 3);
    const uint16_t* Asrc[2];
    const uint16_t* Bsrc[2];
#pragma unroll
    for (int i = 0; i < 2; ++i) {
        const int row = wave * 32 + i * 16 + l2;
        int m = mtile * 128 + row;
        if (m >= MTOT) m = MTOT - 1;
        const int oh = m / OWD, ow = m - oh * OWD;
        Asrc[i] = Xbf + (((size_t)b * 128 + oh) * 128 + ow) * 128 + kc * 8;
        Bsrc[i] = Bt + ((size_t)b * 128 + row) * 1152 + kc * 8;
    }
    const int dbase = wave * 1024 + lane * 8;  // elem offset in a buffer

    f32x4 acc[4][4];
#pragma unroll
    for (int i = 0; i < 4; ++i)
#pragma unroll
        for (int j = 0; j < 4; ++j)
            acc[i][j] = (f32x4){0.f, 0.f, 0.f, 0.f};

    // chunk t (0..35): rs = t>>2, ch base c0 = (t&3)*32
#define STAGE(t_, bu_)                                                      \
    {                                                                       \
        const int rs_ = (t_) >> 2;                                         \
        const int c0_ = ((t_) & 3) << 5;                                   \
        const int r_  = (rs_ * 11) >> 5; /* rs/3 for rs<9 */               \
        const int s_  = rs_ - r_ * 3;                                      \
        const int ao_ = (r_ * 128 + s_) * 128 + c0_;                       \
        const int bo_ = rs_ * 128 + c0_;                                   \
        uint16_t* Ad_ = &lds[bu_][dbase];                                  \
        uint16_t* Bd_ = &lds[bu_][4096 + dbase];                           \
        _Pragma("unroll")                                                  \
        for (int i_ = 0; i_ < 2; ++i_) {                                   \
            gl_lds16(Asrc[i_] + ao_, Ad_ + i_ * 512);                      \
            gl_lds16(Bsrc[i_] + bo_, Bd_ + i_ * 512);                      \
        }                                                                  \
    }

#define COMPUTE(bu_)                                                        \
    {                                                                       \
        bf16x8 af[4], bfr[4];                                              \
        _Pragma("unroll")                                                  \
        for (int i_ = 0; i_ < 4; ++i_) {                                   \
            const int row_ = wm + i_ * 16 + l15;                           \
            const int sl_  = quad ^ ((row_ >> 1) & 3);                     \
            af[i_] = *(const bf16x8*)&lds[bu_][row_ * 32 + sl_ * 8];       \
        }                                                                  \
        _Pragma("unroll")                                                  \
        for (int j_ = 0; j_ < 4; ++j_) {                                   \
            const int row_ = wn + j_ * 16 + l15;                           \
            const int sl_  = quad ^ ((row_ >> 1) & 3);                     \
            bfr[j_] = *(const bf16x8*)&lds[bu_][4096 + row_ * 32 + sl_ * 8];\
        }                                                                  \
        _Pragma("unroll")                                                  \
        for (int i_ = 0; i_ < 4; ++i_)                                     \
            _Pragma("unroll")                                              \
            for (int j_ = 0; j_ < 4; ++j_)                                 \
                acc[i_][j_] = __builtin_amdgcn_mfma_f32_16x16x32_bf16(     \
                    af[i_], bfr[j_], acc[i_][j_], 0, 0, 0);                \
    }

#define WAITBAR4                                                            \
    asm volatile("s_waitcnt vmcnt(4)" ::: "memory");                       \
    __builtin_amdgcn_s_barrier();                                          \
    __builtin_amdgcn_sched_barrier(0);

#define ITER(t_, bc_, bs_)                                                  \
    {                                                                       \
        WAITBAR4;                                                          \
        STAGE((t_) + 2, bs_);                                              \
        COMPUTE(bc_);                                                      \
    }

    // prologue: chunks 0,1 into bufs 0,1 (8 loads in flight)
    STAGE(0, 0);
    STAGE(1, 1);

    // steady state: compute t from buf t%3, stage t+2 into (t+2)%3.
    // At each wait: outstanding = chunk t (4) + chunk t+1 (4); vmcnt(4)
    // drains t's, leaves t+1's in flight across the barrier.
#pragma unroll 1
    for (int t = 0; t < 33; t += 3) {
        ITER(t, 0, 2);
        ITER(t + 1, 1, 0);
        ITER(t + 2, 2, 1);
    }
    ITER(33, 0, 2);  // stages chunk 35 into buf 2
    // t = 34: outstanding = 34's + 35's -> drain 34's
    WAITBAR4;
    COMPUTE(1);
    // t = 35: drain the last 4
    asm volatile("s_waitcnt vmcnt(0)" ::: "memory");
    __builtin_amdgcn_s_barrier();
    __builtin_amdgcn_sched_barrier(0);
    COMPUTE(2);

#undef STAGE
#undef COMPUTE
#undef WAITBAR4
#undef ITER

    // epilogue: D row = quad*4+reg, col = lane&15 (verified)
#pragma unroll
    for (int i = 0; i < 4; ++i) {
#pragma unroll
        for (int rr = 0; rr < 4; ++rr) {
            const int mrow = mtile * 128 + wm + i * 16 + quad * 4 + rr;
            if (mrow < MTOT) {
                const int oh2 = mrow / OWD;
                const int ow2 = mrow - oh2 * OWD;
                float* op = Out + (((size_t)b * OWD + oh2) * OWD + ow2) * 128 + wn + l15;
#pragma unroll
                for (int j = 0; j < 4; ++j)
                    op[j * 16] = acc[i][j][rr];
            }
        }
    }
}

// ---------------------------------------------------------------------------
// Fallback (ws too small): fp32 X with in-kernel cvt (unchanged, verified).
// ---------------------------------------------------------------------------
__global__ __launch_bounds__(256) void conv_mfma(const float* __restrict__ X,
                                                 const uint16_t* __restrict__ Bt,
                                                 float* __restrict__ Out) {
    __shared__ __align__(16) uint16_t lA[128 * 64];
    __shared__ __align__(16) uint16_t lB[128 * 64];

    const int mtile = blockIdx.x;
    const int b     = blockIdx.y;
    const int tid   = threadIdx.x;
    const int lane  = tid & 63;
    const int wave  = tid >> 6;
    const int wm    = (wave & 1) << 6;
    const int wn    = (wave >> 1) << 6;
    const int l15   = lane & 15;
    const int quad  = lane >> 4;

    const int srow  = tid >> 1;
    const int shalf = tid & 1;

    int m = mtile * 128 + srow;
    if (m >= MTOT) m = MTOT - 1;
    const int oh = m / OWD;
    const int ow = m - oh * OWD;
    const float*    Xb = X + (((size_t)b * 128 + oh) * 128 + ow) * 128;
    const uint16_t* Bb = Bt + ((size_t)b * 128 + srow) * 1152 + shalf * 32;

    f32x4 acc[4][4];
#pragma unroll
    for (int i = 0; i < 4; ++i)
#pragma unroll
        for (int j = 0; j < 4; ++j)
            acc[i][j] = (f32x4){0.f, 0.f, 0.f, 0.f};

    for (int chunk = 0; chunk < 18; ++chunk) {
        const int rs = chunk >> 1;
        const int c0 = (chunk & 1) << 6;
        const int r  = rs / 3;
        const int s  = rs - r * 3;

        __syncthreads();
        {
            const float4* src = (const float4*)(Xb + (r * 128 + s) * 128 + c0 + shalf * 32);
            float4 v[8];
#pragma unroll
            for (int i = 0; i < 8; ++i) v[i] = src[i];
#pragma unroll
            for (int i = 0; i < 4; ++i) {
                uint4 p;
                p.x = pk2(v[2 * i].x, v[2 * i].y);
                p.y = pk2(v[2 * i].z, v[2 * i].w);
                p.z = pk2(v[2 * i + 1].x, v[2 * i + 1].y);
                p.w = pk2(v[2 * i + 1].z, v[2 * i + 1].w);
                const int ci = (shalf * 4 + i) ^ (srow & 7);
                *(uint4*)&lA[srow * 64 + ci * 8] = p;
            }
        }
        {
            const uint4* bsrc = (const uint4*)(Bb + rs * 128 + c0);
#pragma unroll
            for (int i = 0; i < 4; ++i) {
                const uint4 p = bsrc[i];
                const int ci = (shalf * 4 + i) ^ (srow & 7);
                *(uint4*)&lB[srow * 64 + ci * 8] = p;
            }
        }
        __syncthreads();

#pragma unroll
        for (int ksub = 0; ksub < 2; ++ksub) {
            bf16x8 af[4], bfr[4];
#pragma unroll
            for (int i = 0; i < 4; ++i) {
                const int row = wm + i * 16 + l15;
                const int ci  = (ksub * 4 + quad) ^ (row & 7);
                af[i] = *(const bf16x8*)&lA[row * 64 + ci * 8];
            }
#pragma unroll
            for (int j = 0; j < 4; ++j) {
                const int row = wn + j * 16 + l15;
                const int ci  = (ksub * 4 + quad) ^ (row & 7);
                bfr[j] = *(const bf16x8*)&lB[row * 64 + ci * 8];
            }
#pragma unroll
            for (int i = 0; i < 4; ++i)
#pragma unroll
                for (int j = 0; j < 4; ++j)
                    acc[i][j] = __builtin_amdgcn_mfma_f32_16x16x32_bf16(
                        af[i], bfr[j], acc[i][j], 0, 0, 0);
        }
    }

#pragma unroll
    for (int i = 0; i < 4; ++i) {
#pragma unroll
        for (int rr = 0; rr < 4; ++rr) {
            const int mrow = mtile * 128 + wm + i * 16 + quad * 4 + rr;
            if (mrow < MTOT) {
                const int oh2 = mrow / OWD;
                const int ow2 = mrow - oh2 * OWD;
                float* op = Out + (((size_t)b * OWD + oh2) * OWD + ow2) * 128 + wn + l15;
#pragma unroll
                for (int j = 0; j < 4; ++j)
                    op[j * 16] = acc[i][j][rr];
            }
        }
    }
}

extern "C" void kernel_launch(void* const* d_in, const int* in_sizes, int n_in,
                              void* d_out, int out_size, void* d_ws, size_t ws_size,
                              hipStream_t stream) {
    const float* X   = (const float*)d_in[0];   // [16,128,128,128]
    const float* Kin = (const float*)d_in[1];   // [16,3,3,128,128]
    float*       Out = (float*)d_out;           // [16,126,126,128]
    uint16_t*    Bt  = (uint16_t*)d_ws;         // bf16 [16][128][1152]
    uint16_t*    Xbf = Bt + BT_ELEMS;           // bf16 [16][128][128][128]

    kprep<<<dim3(9, 16), 256, 0, stream>>>(Kin, Bt);
    if (ws_size >= WS_NEEDED) {
        xprep<<<XBF_ELEMS / (256 * 8), 256, 0, stream>>>(X, Xbf);
        conv_mfma_c<<<dim3(125, 16), 256, 0, stream>>>(Xbf, Bt, Out);
    } else {
        conv_mfma<<<dim3(125, 16), 256, 0, stream>>>(X, Bt, Out);
    }
}